// Round 1
// baseline (664.893 us; speedup 1.0000x reference)
//
#include <hip/hip_runtime.h>
#include <hip/hip_bf16.h>
#include <math.h>

#define BB 64
#define PP 8732
#define CC 81
#define NOBJ 32
#define NSORT 16384

__device__ __forceinline__ float sl1(float x) {
    float ax = fabsf(x);
    return (ax < 1.0f) ? 0.5f * x * x : ax - 0.5f;
}

// ---------------- Kernel 1: matching + loc loss -----------------
__global__ __launch_bounds__(256) void k_match(
    const float* __restrict__ loc_pred,   // [B,P,4]
    const float* __restrict__ gt_boxes,   // [B,NOBJ,4] xyxy
    const int*   __restrict__ gt_labels,  // [B,NOBJ]
    const float* __restrict__ dbox,       // [P,4] cxcywh
    int*   __restrict__ true_label,       // [B,P]
    int*   __restrict__ n_pos,            // [B]
    float* __restrict__ acc,              // [0]=loc_sum,[1]=conf_pos,[2]=conf_hard
    int*   __restrict__ n_pos_total)
{
    __shared__ float s_ov[PP];
    __shared__ unsigned char s_obj[PP];
    __shared__ float s_gx0[NOBJ], s_gy0[NOBJ], s_gx1[NOBJ], s_gy1[NOBJ], s_garea[NOBJ];
    __shared__ float s_gcx[NOBJ], s_gcy[NOBJ], s_gw[NOBJ], s_gh[NOBJ];
    __shared__ int   s_glbl[NOBJ];
    __shared__ int   s_bp[NOBJ];
    __shared__ float red_f[256];
    __shared__ int   red_i[256];

    const int b   = blockIdx.x;
    const int tid = threadIdx.x;

    if (tid < NOBJ) {
        float x0 = gt_boxes[(b * NOBJ + tid) * 4 + 0];
        float y0 = gt_boxes[(b * NOBJ + tid) * 4 + 1];
        float x1 = gt_boxes[(b * NOBJ + tid) * 4 + 2];
        float y1 = gt_boxes[(b * NOBJ + tid) * 4 + 3];
        s_gx0[tid] = x0; s_gy0[tid] = y0; s_gx1[tid] = x1; s_gy1[tid] = y1;
        s_garea[tid] = (x1 - x0) * (y1 - y0);
        s_gcx[tid] = (x0 + x1) * 0.5f;
        s_gcy[tid] = (y0 + y1) * 0.5f;
        s_gw[tid]  = x1 - x0;
        s_gh[tid]  = y1 - y0;
        s_glbl[tid] = gt_labels[b * NOBJ + tid];
    }
    __syncthreads();

    // Pass A: per-prior best object (argmax over axis 0, first occurrence)
    for (int p = tid; p < PP; p += 256) {
        float4 db = reinterpret_cast<const float4*>(dbox)[p];
        float px0 = db.x - db.z * 0.5f, py0 = db.y - db.w * 0.5f;
        float px1 = db.x + db.z * 0.5f, py1 = db.y + db.w * 0.5f;
        float parea = db.z * db.w;
        float best = -1.0f; int bo = 0;
#pragma unroll
        for (int o = 0; o < NOBJ; ++o) {
            float lx = fmaxf(px0, s_gx0[o]);
            float ly = fmaxf(py0, s_gy0[o]);
            float rx = fminf(px1, s_gx1[o]);
            float ry = fminf(py1, s_gy1[o]);
            float w = fmaxf(rx - lx, 0.0f);
            float h = fmaxf(ry - ly, 0.0f);
            float inter = w * h;
            float iou = inter / (s_garea[o] + parea - inter);
            if (iou > best) { best = iou; bo = o; }   // strict > => first max
        }
        s_ov[p] = best;
        s_obj[p] = (unsigned char)bo;
    }
    __syncthreads();

    // Pass B: per-object best prior (argmax over axis 1, tie -> min p)
    const int wave = tid >> 6, lane = tid & 63;
    for (int o = wave; o < NOBJ; o += 4) {
        float gx0 = s_gx0[o], gy0 = s_gy0[o], gx1 = s_gx1[o], gy1 = s_gy1[o];
        float garea = s_garea[o];
        float best = -1.0f; int bp = 0x7fffffff;
        for (int p = lane; p < PP; p += 64) {
            float4 db = reinterpret_cast<const float4*>(dbox)[p];
            float px0 = db.x - db.z * 0.5f, py0 = db.y - db.w * 0.5f;
            float px1 = db.x + db.z * 0.5f, py1 = db.y + db.w * 0.5f;
            float parea = db.z * db.w;
            float lx = fmaxf(px0, gx0);
            float ly = fmaxf(py0, gy0);
            float rx = fminf(px1, gx1);
            float ry = fminf(py1, gy1);
            float w = fmaxf(rx - lx, 0.0f);
            float h = fmaxf(ry - ly, 0.0f);
            float inter = w * h;
            float iou = inter / (garea + parea - inter);
            if (iou > best) { best = iou; bp = p; }  // p ascending per lane
        }
#pragma unroll
        for (int m = 32; m > 0; m >>= 1) {
            float ov = __shfl_xor(best, m);
            int   op = __shfl_xor(bp, m);
            if (ov > best || (ov == best && op < bp)) { best = ov; bp = op; }
        }
        if (lane == 0) s_bp[o] = bp;
    }
    __syncthreads();

    // Fixup: sequential, last write wins (matches numpy fancy-assign)
    if (tid == 0) {
        for (int o = 0; o < NOBJ; ++o) {
            int bp = s_bp[o];
            s_obj[bp] = (unsigned char)o;
            s_ov[bp]  = 1.0f;
        }
    }
    __syncthreads();

    // Pass C: labels, loc loss for positives
    float loc_local = 0.0f;
    int   np_local  = 0;
    for (int p = tid; p < PP; p += 256) {
        int o = s_obj[p];
        int lbl = (s_ov[p] < 0.5f) ? 0 : s_glbl[o];
        true_label[b * PP + p] = lbl;
        if (lbl > 0) {
            np_local++;
            float4 db = reinterpret_cast<const float4*>(dbox)[p];
            float g0 = (s_gcx[o] - db.x) / (db.z / 10.0f);
            float g1 = (s_gcy[o] - db.y) / (db.w / 10.0f);
            float g2 = logf(s_gw[o] / db.z) * 5.0f;
            float g3 = logf(s_gh[o] / db.w) * 5.0f;
            float4 lp = reinterpret_cast<const float4*>(loc_pred)[b * PP + p];
            loc_local += sl1(lp.x - g0) + sl1(lp.y - g1) + sl1(lp.z - g2) + sl1(lp.w - g3);
        }
    }
    red_f[tid] = loc_local;
    red_i[tid] = np_local;
    __syncthreads();
#pragma unroll
    for (int st = 128; st > 0; st >>= 1) {
        if (tid < st) { red_f[tid] += red_f[tid + st]; red_i[tid] += red_i[tid + st]; }
        __syncthreads();
    }
    if (tid == 0) {
        n_pos[b] = red_i[0];
        atomicAdd(&acc[0], red_f[0]);
        atomicAdd(n_pos_total, red_i[0]);
    }
}

// ---------------- Kernel 2: cross entropy, wave per prior -----------------
__global__ __launch_bounds__(256) void k_ce(
    const float* __restrict__ cls_pred,   // [B,P,C]
    const int*   __restrict__ true_label, // [B,P]
    float* __restrict__ ce_neg,           // [B,P]
    float* __restrict__ acc)              // [1]=conf_pos
{
    __shared__ float s_pos;
    if (threadIdx.x == 0) s_pos = 0.0f;
    __syncthreads();

    const int lane = threadIdx.x & 63;
    const int wave = threadIdx.x >> 6;
    const long long total = (long long)BB * PP;
    const long long stride = (long long)gridDim.x * 4;
    float local = 0.0f;

    for (long long idx = (long long)blockIdx.x * 4 + wave; idx < total; idx += stride) {
        const float* x = cls_pred + idx * CC;
        float x0 = x[lane];
        float x1 = (lane + 64 < CC) ? x[lane + 64] : -1e30f;
        float m = fmaxf(x0, x1);
#pragma unroll
        for (int s = 32; s > 0; s >>= 1) m = fmaxf(m, __shfl_xor(m, s));
        float e = expf(x0 - m) + ((lane + 64 < CC) ? expf(x1 - m) : 0.0f);
#pragma unroll
        for (int s = 32; s > 0; s >>= 1) e += __shfl_xor(e, s);
        int lbl = true_label[idx];
        float xl = __shfl((lbl < 64) ? x0 : x1, lbl & 63);
        float ce = logf(e) + m - xl;
        if (lane == 0) {
            if (lbl > 0) { local += ce; ce_neg[idx] = 0.0f; }
            else ce_neg[idx] = ce;
        }
    }
    if (lane == 0 && local != 0.0f) atomicAdd(&s_pos, local);
    __syncthreads();
    if (threadIdx.x == 0) atomicAdd(&acc[1], s_pos);
}

// ---------------- Kernel 3: per-image top-K sum via bitonic sort ---------
__global__ __launch_bounds__(1024) void k_topk(
    const float* __restrict__ ce_neg,  // [B,P]
    const int*   __restrict__ n_pos,   // [B]
    float* __restrict__ acc)           // [2]=conf_hard
{
    __shared__ float s[NSORT];
    const int b = blockIdx.x, tid = threadIdx.x;

    for (int i = tid; i < NSORT; i += 1024)
        s[i] = (i < PP) ? ce_neg[b * PP + i] : -1.0f;   // ce >= 0, pad low
    __syncthreads();

    for (int k = 2; k <= NSORT; k <<= 1) {
        for (int j = k >> 1; j > 0; j >>= 1) {
            for (int i = tid; i < NSORT; i += 1024) {
                int ixj = i ^ j;
                if (ixj > i) {
                    float a = s[i], c = s[ixj];
                    bool asc = ((i & k) == 0);
                    if (asc ? (a > c) : (a < c)) { s[i] = c; s[ixj] = a; }
                }
            }
            __syncthreads();
        }
    }

    int K = n_pos[b] * 3;
    if (K > PP) K = PP;
    float local = 0.0f;
    for (int r = tid; r < K; r += 1024) local += s[NSORT - 1 - r];
    __syncthreads();
    s[tid] = local;
    __syncthreads();
#pragma unroll
    for (int st = 512; st > 0; st >>= 1) {
        if (tid < st) s[tid] += s[tid + st];
        __syncthreads();
    }
    if (tid == 0) atomicAdd(&acc[2], s[0]);
}

// ---------------- Kernel 4: finalize -----------------
__global__ void k_final(const float* __restrict__ acc,
                        const int* __restrict__ n_pos_total,
                        float* __restrict__ out)
{
    float npt = (float)(*n_pos_total);
    float loc_loss  = acc[0] / (npt * 4.0f);
    float conf_loss = (acc[1] + acc[2]) / npt;
    out[0] = conf_loss + loc_loss;
}

extern "C" void kernel_launch(void* const* d_in, const int* in_sizes, int n_in,
                              void* d_out, int out_size, void* d_ws, size_t ws_size,
                              hipStream_t stream) {
    const float* loc_pred  = (const float*)d_in[0];
    const float* cls_pred  = (const float*)d_in[1];
    const float* gt_boxes  = (const float*)d_in[2];
    const int*   gt_labels = (const int*)d_in[3];
    const float* dbox      = (const float*)d_in[4];
    float* out = (float*)d_out;

    // workspace layout
    float* acc        = (float*)d_ws;                 // 3 floats
    int*   npt        = (int*)d_ws + 3;               // 1 int
    int*   n_pos      = (int*)d_ws + 4;               // B ints
    int*   true_label = (int*)d_ws + 4 + BB;          // B*P ints
    float* ce_neg     = (float*)((int*)d_ws + 4 + BB + (size_t)BB * PP);

    hipMemsetAsync(d_ws, 0, 16, stream);  // zero acc[0..2] + n_pos_total

    k_match<<<BB, 256, 0, stream>>>(loc_pred, gt_boxes, gt_labels, dbox,
                                    true_label, n_pos, acc, npt);
    k_ce<<<2048, 256, 0, stream>>>(cls_pred, true_label, ce_neg, acc);
    k_topk<<<BB, 1024, 0, stream>>>(ce_neg, n_pos, acc);
    k_final<<<1, 1, 0, stream>>>(acc, npt, out);
}

// Round 2
// 281.243 us; speedup vs baseline: 2.3641x; 2.3641x over previous
//
#include <hip/hip_runtime.h>
#include <hip/hip_bf16.h>
#include <math.h>

#define BB 64
#define PP 8732
#define CC 81
#define NOBJ 32
#define CHUNKS ((PP + 255) / 256)   // 35

__device__ __forceinline__ float sl1(float x) {
    float ax = fabsf(x);
    return (ax < 1.0f) ? 0.5f * x * x : ax - 0.5f;
}

// ---------- Kernel 1: per-object best prior (one wave per (b,o)) ----------
__global__ __launch_bounds__(256) void k_bestprior(
    const float* __restrict__ gt_boxes,   // [B,NOBJ,4] xyxy
    const float* __restrict__ dbox,       // [P,4] cxcywh
    int* __restrict__ bp)                 // [B,NOBJ]
{
    const int wave = threadIdx.x >> 6, lane = threadIdx.x & 63;
    const int b = blockIdx.x >> 3;                 // / 8
    const int o = ((blockIdx.x & 7) << 2) + wave;  // 8 groups * 4 waves = 32 objects

    const float* g = gt_boxes + (b * NOBJ + o) * 4;
    float gx0 = g[0], gy0 = g[1], gx1 = g[2], gy1 = g[3];
    float garea = (gx1 - gx0) * (gy1 - gy0);

    float best = -1.0f; int bpp = 0x7fffffff;
    for (int p = lane; p < PP; p += 64) {
        float4 db = reinterpret_cast<const float4*>(dbox)[p];
        float px0 = db.x - db.z * 0.5f, py0 = db.y - db.w * 0.5f;
        float px1 = db.x + db.z * 0.5f, py1 = db.y + db.w * 0.5f;
        float parea = db.z * db.w;
        float lx = fmaxf(px0, gx0), ly = fmaxf(py0, gy0);
        float rx = fminf(px1, gx1), ry = fminf(py1, gy1);
        float w = fmaxf(rx - lx, 0.0f), h = fmaxf(ry - ly, 0.0f);
        float inter = w * h;
        float iou = inter / (garea + parea - inter);
        if (iou > best) { best = iou; bpp = p; }   // p ascending per lane => first max
    }
#pragma unroll
    for (int m = 32; m > 0; m >>= 1) {
        float ov = __shfl_xor(best, m);
        int   op = __shfl_xor(bpp, m);
        if (ov > best || (ov == best && op < bpp)) { best = ov; bpp = op; }
    }
    if (lane == 0) bp[b * NOBJ + o] = bpp;
}

// ---------- Kernel 2: per-prior assignment + loc loss (thread per prior) ----------
__global__ __launch_bounds__(256) void k_assign(
    const float* __restrict__ loc_pred,   // [B,P,4]
    const float* __restrict__ gt_boxes,   // [B,NOBJ,4]
    const int*   __restrict__ gt_labels,  // [B,NOBJ]
    const float* __restrict__ dbox,       // [P,4]
    const int*   __restrict__ bp,         // [B,NOBJ]
    int*   __restrict__ true_label,       // [B,P]
    int*   __restrict__ n_pos,            // [B]
    float* __restrict__ acc,              // [0]=loc_sum
    int*   __restrict__ n_pos_total)
{
    __shared__ float s_gx0[NOBJ], s_gy0[NOBJ], s_gx1[NOBJ], s_gy1[NOBJ], s_garea[NOBJ];
    __shared__ float s_gcx[NOBJ], s_gcy[NOBJ], s_gw[NOBJ], s_gh[NOBJ];
    __shared__ int   s_glbl[NOBJ], s_bp[NOBJ];
    __shared__ float red_f[256];
    __shared__ int   red_i[256];

    const int b     = blockIdx.x / CHUNKS;
    const int chunk = blockIdx.x % CHUNKS;
    const int tid   = threadIdx.x;
    const int p     = chunk * 256 + tid;

    if (tid < NOBJ) {
        float x0 = gt_boxes[(b * NOBJ + tid) * 4 + 0];
        float y0 = gt_boxes[(b * NOBJ + tid) * 4 + 1];
        float x1 = gt_boxes[(b * NOBJ + tid) * 4 + 2];
        float y1 = gt_boxes[(b * NOBJ + tid) * 4 + 3];
        s_gx0[tid] = x0; s_gy0[tid] = y0; s_gx1[tid] = x1; s_gy1[tid] = y1;
        s_garea[tid] = (x1 - x0) * (y1 - y0);
        s_gcx[tid] = (x0 + x1) * 0.5f;
        s_gcy[tid] = (y0 + y1) * 0.5f;
        s_gw[tid]  = x1 - x0;
        s_gh[tid]  = y1 - y0;
        s_glbl[tid] = gt_labels[b * NOBJ + tid];
        s_bp[tid]   = bp[b * NOBJ + tid];
    }
    __syncthreads();

    float loc_local = 0.0f;
    int   np_local  = 0;

    if (p < PP) {
        float4 db = reinterpret_cast<const float4*>(dbox)[p];
        float px0 = db.x - db.z * 0.5f, py0 = db.y - db.w * 0.5f;
        float px1 = db.x + db.z * 0.5f, py1 = db.y + db.w * 0.5f;
        float parea = db.z * db.w;

        float best = -1.0f; int bo = 0;
#pragma unroll
        for (int o = 0; o < NOBJ; ++o) {
            float lx = fmaxf(px0, s_gx0[o]), ly = fmaxf(py0, s_gy0[o]);
            float rx = fminf(px1, s_gx1[o]), ry = fminf(py1, s_gy1[o]);
            float w = fmaxf(rx - lx, 0.0f), h = fmaxf(ry - ly, 0.0f);
            float inter = w * h;
            float iou = inter / (s_garea[o] + parea - inter);
            if (iou > best) { best = iou; bo = o; }  // strict > => first occurrence
        }
        // forced-match fixup: last o with bp[o]==p wins (numpy last-write-wins)
        int forced = -1;
#pragma unroll
        for (int o = 0; o < NOBJ; ++o)
            if (s_bp[o] == p) forced = o;

        int o_use, lbl;
        if (forced >= 0) { o_use = forced; lbl = s_glbl[forced]; }   // ov forced to 1.0
        else             { o_use = bo; lbl = (best < 0.5f) ? 0 : s_glbl[bo]; }

        true_label[b * PP + p] = lbl;
        if (lbl > 0) {
            np_local = 1;
            float g0 = (s_gcx[o_use] - db.x) / (db.z / 10.0f);
            float g1 = (s_gcy[o_use] - db.y) / (db.w / 10.0f);
            float g2 = logf(s_gw[o_use] / db.z) * 5.0f;
            float g3 = logf(s_gh[o_use] / db.w) * 5.0f;
            float4 lp = reinterpret_cast<const float4*>(loc_pred)[b * PP + p];
            loc_local = sl1(lp.x - g0) + sl1(lp.y - g1) + sl1(lp.z - g2) + sl1(lp.w - g3);
        }
    }

    red_f[tid] = loc_local;
    red_i[tid] = np_local;
    __syncthreads();
#pragma unroll
    for (int st = 128; st > 0; st >>= 1) {
        if (tid < st) { red_f[tid] += red_f[tid + st]; red_i[tid] += red_i[tid + st]; }
        __syncthreads();
    }
    if (tid == 0) {
        atomicAdd(&acc[0], red_f[0]);
        atomicAdd(&n_pos[b], red_i[0]);
        atomicAdd(n_pos_total, red_i[0]);
    }
}

// ---------- Kernel 3: cross entropy, wave per prior ----------
__global__ __launch_bounds__(256) void k_ce(
    const float* __restrict__ cls_pred,   // [B,P,C]
    const int*   __restrict__ true_label, // [B,P]
    float* __restrict__ ce_neg,           // [B,P]
    float* __restrict__ acc)              // [1]=conf_pos
{
    __shared__ float s_pos;
    if (threadIdx.x == 0) s_pos = 0.0f;
    __syncthreads();

    const int lane = threadIdx.x & 63;
    const int wave = threadIdx.x >> 6;
    const long long total = (long long)BB * PP;
    const long long stride = (long long)gridDim.x * 4;
    float local = 0.0f;

    for (long long idx = (long long)blockIdx.x * 4 + wave; idx < total; idx += stride) {
        const float* x = cls_pred + idx * CC;
        float x0 = x[lane];
        float x1 = (lane + 64 < CC) ? x[lane + 64] : -1e30f;
        float m = fmaxf(x0, x1);
#pragma unroll
        for (int s = 32; s > 0; s >>= 1) m = fmaxf(m, __shfl_xor(m, s));
        float e = expf(x0 - m) + ((lane + 64 < CC) ? expf(x1 - m) : 0.0f);
#pragma unroll
        for (int s = 32; s > 0; s >>= 1) e += __shfl_xor(e, s);
        int lbl = true_label[idx];
        float xl = __shfl((lbl < 64) ? x0 : x1, lbl & 63);
        float ce = logf(e) + m - xl;
        if (lane == 0) {
            if (lbl > 0) { local += ce; ce_neg[idx] = 0.0f; }
            else ce_neg[idx] = ce;
        }
    }
    if (lane == 0 && local != 0.0f) atomicAdd(&s_pos, local);
    __syncthreads();
    if (threadIdx.x == 0) atomicAdd(&acc[1], s_pos);
}

// ---------- Kernel 4: per-image top-K sum via radix select ----------
__global__ __launch_bounds__(256) void k_select(
    const float* __restrict__ ce_neg,  // [B,P]
    const int*   __restrict__ n_pos,   // [B]
    float* __restrict__ acc)           // [2]=conf_hard
{
    __shared__ unsigned int sv[PP];
    __shared__ unsigned int hist[256];
    __shared__ unsigned int s_prefix, s_krem;
    __shared__ float red_f[256];
    __shared__ int   red_i[256];

    const int b = blockIdx.x, tid = threadIdx.x;

    for (int i = tid; i < PP; i += 256)
        sv[i] = __float_as_uint(ce_neg[b * PP + i]);   // all values >= 0

    int K = n_pos[b] * 3;
    if (K > PP) K = PP;
    if (K <= 0) return;
    __syncthreads();

    // radix select: find K-th largest (bits of non-negative floats order as uints)
    unsigned int prefix = 0, krem = (unsigned int)K;
    for (int shift = 24; shift >= 0; shift -= 8) {
        hist[tid] = 0;
        __syncthreads();
        unsigned int mask_hi = (shift == 24) ? 0u : (0xFFFFFFFFu << (shift + 8));
        for (int i = tid; i < PP; i += 256) {
            unsigned int v = sv[i];
            if ((v & mask_hi) == prefix) atomicAdd(&hist[(v >> shift) & 0xFFu], 1u);
        }
        __syncthreads();
        if (tid == 0) {
            unsigned int kr = krem, bin = 255;
            for (int bb = 255; bb >= 0; --bb) {
                unsigned int c = hist[bb];
                if (c >= kr) { bin = (unsigned int)bb; break; }
                kr -= c;
            }
            s_prefix = prefix | (bin << shift);
            s_krem = kr;
        }
        __syncthreads();
        prefix = s_prefix; krem = s_krem;
    }
    float cutoff = __uint_as_float(prefix);

    // exact top-K sum: sum(v > c) + (K - cnt_gt) * c   (ties all equal c)
    float sum_gt = 0.0f; int cnt_gt = 0;
    for (int i = tid; i < PP; i += 256) {
        float v = __uint_as_float(sv[i]);
        if (v > cutoff) { sum_gt += v; cnt_gt++; }
    }
    red_f[tid] = sum_gt; red_i[tid] = cnt_gt;
    __syncthreads();
#pragma unroll
    for (int st = 128; st > 0; st >>= 1) {
        if (tid < st) { red_f[tid] += red_f[tid + st]; red_i[tid] += red_i[tid + st]; }
        __syncthreads();
    }
    if (tid == 0)
        atomicAdd(&acc[2], red_f[0] + (float)(K - red_i[0]) * cutoff);
}

// ---------- Kernel 5: finalize ----------
__global__ void k_final(const float* __restrict__ acc,
                        const int* __restrict__ n_pos_total,
                        float* __restrict__ out)
{
    float npt = (float)(*n_pos_total);
    float loc_loss  = acc[0] / (npt * 4.0f);
    float conf_loss = (acc[1] + acc[2]) / npt;
    out[0] = conf_loss + loc_loss;
}

extern "C" void kernel_launch(void* const* d_in, const int* in_sizes, int n_in,
                              void* d_out, int out_size, void* d_ws, size_t ws_size,
                              hipStream_t stream) {
    const float* loc_pred  = (const float*)d_in[0];
    const float* cls_pred  = (const float*)d_in[1];
    const float* gt_boxes  = (const float*)d_in[2];
    const int*   gt_labels = (const int*)d_in[3];
    const float* dbox      = (const float*)d_in[4];
    float* out = (float*)d_out;

    // workspace layout
    float* acc        = (float*)d_ws;                       // 3 floats
    int*   npt        = (int*)d_ws + 3;                     // 1
    int*   n_pos      = (int*)d_ws + 4;                     // BB
    int*   bp         = (int*)d_ws + 4 + BB;                // BB*NOBJ
    int*   true_label = (int*)d_ws + 4 + BB + BB * NOBJ;    // BB*PP
    float* ce_neg     = (float*)((int*)d_ws + 4 + BB + BB * NOBJ + (size_t)BB * PP);

    hipMemsetAsync(d_ws, 0, (4 + BB) * sizeof(int), stream);  // acc, npt, n_pos

    k_bestprior<<<BB * (NOBJ / 4), 256, 0, stream>>>(gt_boxes, dbox, bp);
    k_assign<<<BB * CHUNKS, 256, 0, stream>>>(loc_pred, gt_boxes, gt_labels, dbox, bp,
                                              true_label, n_pos, acc, npt);
    k_ce<<<2048, 256, 0, stream>>>(cls_pred, true_label, ce_neg, acc);
    k_select<<<BB, 256, 0, stream>>>(ce_neg, n_pos, acc);
    k_final<<<1, 1, 0, stream>>>(acc, npt, out);
}

// Round 3
// 275.695 us; speedup vs baseline: 2.4117x; 1.0201x over previous
//
#include <hip/hip_runtime.h>
#include <hip/hip_bf16.h>
#include <math.h>

#define BB 64
#define PP 8732
#define CC 81
#define NOBJ 32
#define CHUNKS ((PP + 255) / 256)   // 35
#define NPRI (BB * PP)              // 558848, divisible by 4

__device__ __forceinline__ float sl1(float x) {
    float ax = fabsf(x);
    return (ax < 1.0f) ? 0.5f * x * x : ax - 0.5f;
}

// ---------- Kernel 1: per-object best prior (one wave per (b,o)) ----------
__global__ __launch_bounds__(256) void k_bestprior(
    const float* __restrict__ gt_boxes,   // [B,NOBJ,4] xyxy
    const float* __restrict__ dbox,       // [P,4] cxcywh
    int* __restrict__ bp)                 // [B,NOBJ]
{
    const int wave = threadIdx.x >> 6, lane = threadIdx.x & 63;
    const int b = blockIdx.x >> 3;
    const int o = ((blockIdx.x & 7) << 2) + wave;

    const float* g = gt_boxes + (b * NOBJ + o) * 4;
    float gx0 = g[0], gy0 = g[1], gx1 = g[2], gy1 = g[3];
    float garea = (gx1 - gx0) * (gy1 - gy0);

    float best = -1.0f; int bpp = 0x7fffffff;
    for (int p = lane; p < PP; p += 64) {
        float4 db = reinterpret_cast<const float4*>(dbox)[p];
        float px0 = db.x - db.z * 0.5f, py0 = db.y - db.w * 0.5f;
        float px1 = db.x + db.z * 0.5f, py1 = db.y + db.w * 0.5f;
        float parea = db.z * db.w;
        float lx = fmaxf(px0, gx0), ly = fmaxf(py0, gy0);
        float rx = fminf(px1, gx1), ry = fminf(py1, gy1);
        float w = fmaxf(rx - lx, 0.0f), h = fmaxf(ry - ly, 0.0f);
        float inter = w * h;
        float iou = inter / (garea + parea - inter);
        if (iou > best) { best = iou; bpp = p; }
    }
#pragma unroll
    for (int m = 32; m > 0; m >>= 1) {
        float ov = __shfl_xor(best, m);
        int   op = __shfl_xor(bpp, m);
        if (ov > best || (ov == best && op < bpp)) { best = ov; bpp = op; }
    }
    if (lane == 0) bp[b * NOBJ + o] = bpp;
}

// ---------- Kernel 2: per-prior assignment + loc loss ----------
__global__ __launch_bounds__(256) void k_assign(
    const float* __restrict__ loc_pred,
    const float* __restrict__ gt_boxes,
    const int*   __restrict__ gt_labels,
    const float* __restrict__ dbox,
    const int*   __restrict__ bp,
    int*   __restrict__ true_label,
    int*   __restrict__ n_pos,
    float* __restrict__ acc,
    int*   __restrict__ n_pos_total)
{
    __shared__ float s_gx0[NOBJ], s_gy0[NOBJ], s_gx1[NOBJ], s_gy1[NOBJ], s_garea[NOBJ];
    __shared__ float s_gcx[NOBJ], s_gcy[NOBJ], s_gw[NOBJ], s_gh[NOBJ];
    __shared__ int   s_glbl[NOBJ], s_bp[NOBJ];
    __shared__ float red_f[256];
    __shared__ int   red_i[256];

    const int b     = blockIdx.x / CHUNKS;
    const int chunk = blockIdx.x % CHUNKS;
    const int tid   = threadIdx.x;
    const int p     = chunk * 256 + tid;

    if (tid < NOBJ) {
        float x0 = gt_boxes[(b * NOBJ + tid) * 4 + 0];
        float y0 = gt_boxes[(b * NOBJ + tid) * 4 + 1];
        float x1 = gt_boxes[(b * NOBJ + tid) * 4 + 2];
        float y1 = gt_boxes[(b * NOBJ + tid) * 4 + 3];
        s_gx0[tid] = x0; s_gy0[tid] = y0; s_gx1[tid] = x1; s_gy1[tid] = y1;
        s_garea[tid] = (x1 - x0) * (y1 - y0);
        s_gcx[tid] = (x0 + x1) * 0.5f;
        s_gcy[tid] = (y0 + y1) * 0.5f;
        s_gw[tid]  = x1 - x0;
        s_gh[tid]  = y1 - y0;
        s_glbl[tid] = gt_labels[b * NOBJ + tid];
        s_bp[tid]   = bp[b * NOBJ + tid];
    }
    __syncthreads();

    float loc_local = 0.0f;
    int   np_local  = 0;

    if (p < PP) {
        float4 db = reinterpret_cast<const float4*>(dbox)[p];
        float px0 = db.x - db.z * 0.5f, py0 = db.y - db.w * 0.5f;
        float px1 = db.x + db.z * 0.5f, py1 = db.y + db.w * 0.5f;
        float parea = db.z * db.w;

        float best = -1.0f; int bo = 0;
#pragma unroll
        for (int o = 0; o < NOBJ; ++o) {
            float lx = fmaxf(px0, s_gx0[o]), ly = fmaxf(py0, s_gy0[o]);
            float rx = fminf(px1, s_gx1[o]), ry = fminf(py1, s_gy1[o]);
            float w = fmaxf(rx - lx, 0.0f), h = fmaxf(ry - ly, 0.0f);
            float inter = w * h;
            float iou = inter / (s_garea[o] + parea - inter);
            if (iou > best) { best = iou; bo = o; }
        }
        int forced = -1;
#pragma unroll
        for (int o = 0; o < NOBJ; ++o)
            if (s_bp[o] == p) forced = o;

        int o_use, lbl;
        if (forced >= 0) { o_use = forced; lbl = s_glbl[forced]; }
        else             { o_use = bo; lbl = (best < 0.5f) ? 0 : s_glbl[bo]; }

        true_label[b * PP + p] = lbl;
        if (lbl > 0) {
            np_local = 1;
            float g0 = (s_gcx[o_use] - db.x) / (db.z / 10.0f);
            float g1 = (s_gcy[o_use] - db.y) / (db.w / 10.0f);
            float g2 = logf(s_gw[o_use] / db.z) * 5.0f;
            float g3 = logf(s_gh[o_use] / db.w) * 5.0f;
            float4 lp = reinterpret_cast<const float4*>(loc_pred)[b * PP + p];
            loc_local = sl1(lp.x - g0) + sl1(lp.y - g1) + sl1(lp.z - g2) + sl1(lp.w - g3);
        }
    }

    red_f[tid] = loc_local;
    red_i[tid] = np_local;
    __syncthreads();
#pragma unroll
    for (int st = 128; st > 0; st >>= 1) {
        if (tid < st) { red_f[tid] += red_f[tid + st]; red_i[tid] += red_i[tid + st]; }
        __syncthreads();
    }
    if (tid == 0) {
        atomicAdd(&acc[0], red_f[0]);
        atomicAdd(&n_pos[b], red_i[0]);
        atomicAdd(n_pos_total, red_i[0]);
    }
}

// ---------- Kernel 3: cross entropy, 16-lane group per prior (4/wave) ----------
__global__ __launch_bounds__(256) void k_ce(
    const float* __restrict__ cls_pred,   // [B,P,C]
    const int*   __restrict__ true_label, // [B,P]
    float* __restrict__ ce_neg,           // [B,P]
    float* __restrict__ acc)              // [1]=conf_pos
{
    const int lane = threadIdx.x & 63;
    const int g    = lane >> 4;           // group in wave (prior)
    const int c    = lane & 15;           // class-lane
    const int wave = threadIdx.x >> 6;
    const int gwave = blockIdx.x * 4 + wave;
    const int nwaves = gridDim.x * 4;
    const int total4 = NPRI / 4;          // 139712

    const float L2E = 1.4426950408889634f;
    const float LN2 = 0.6931471805599453f;
    float local = 0.0f;

    for (int q4 = gwave; q4 < total4; q4 += nwaves) {
        const int pidx = q4 * 4 + g;
        const float* x = cls_pred + (size_t)pidx * CC;

        // lane c owns classes c, c+16, c+32, c+48, c+64; class 80 on c==0 only
        float y0 = x[c]      * L2E;
        float y1 = x[c + 16] * L2E;
        float y2 = x[c + 32] * L2E;
        float y3 = x[c + 48] * L2E;
        float y4 = x[c + 64] * L2E;
        float y5 = (c == 0) ? x[80] * L2E : -3.0e38f;

        float m = fmaxf(fmaxf(fmaxf(y0, y1), fmaxf(y2, y3)), fmaxf(y4, y5));
#pragma unroll
        for (int s = 1; s < 16; s <<= 1) m = fmaxf(m, __shfl_xor(m, s));

        float e = exp2f(y0 - m) + exp2f(y1 - m) + exp2f(y2 - m)
                + exp2f(y3 - m) + exp2f(y4 - m) + exp2f(y5 - m);
#pragma unroll
        for (int s = 1; s < 16; s <<= 1) e += __shfl_xor(e, s);

        int lbl = true_label[pidx];
        int kl = lbl >> 4, cl = lbl & 15;
        float sel = y0;
        sel = (kl == 1) ? y1 : sel;
        sel = (kl == 2) ? y2 : sel;
        sel = (kl == 3) ? y3 : sel;
        sel = (kl == 4) ? y4 : sel;
        sel = (kl == 5) ? y5 : sel;
        float yl = __shfl(sel, (g << 4) | cl);

        float ce = (log2f(e) + m - yl) * LN2;

        if (c == 0) {
            ce_neg[pidx] = (lbl > 0) ? 0.0f : ce;
            local += (lbl > 0) ? ce : 0.0f;
        }
    }

#pragma unroll
    for (int s = 32; s > 0; s >>= 1) local += __shfl_xor(local, s);
    if (lane == 0 && local != 0.0f) atomicAdd(&acc[1], local);
}

// ---------- Kernel 4: per-image top-K sum via radix select ----------
__global__ __launch_bounds__(256) void k_select(
    const float* __restrict__ ce_neg,  // [B,P]
    const int*   __restrict__ n_pos,   // [B]
    float* __restrict__ acc)           // [2]=conf_hard
{
    __shared__ unsigned int sv[PP];
    __shared__ unsigned int hist[256];
    __shared__ unsigned int s_prefix, s_krem;
    __shared__ float red_f[256];
    __shared__ int   red_i[256];

    const int b = blockIdx.x, tid = threadIdx.x;

    for (int i = tid; i < PP; i += 256)
        sv[i] = __float_as_uint(ce_neg[b * PP + i]);   // all values >= 0

    int K = n_pos[b] * 3;
    if (K > PP) K = PP;
    if (K <= 0) return;
    __syncthreads();

    unsigned int prefix = 0, krem = (unsigned int)K;
    for (int shift = 24; shift >= 0; shift -= 8) {
        hist[tid] = 0;
        __syncthreads();
        unsigned int mask_hi = (shift == 24) ? 0u : (0xFFFFFFFFu << (shift + 8));
        for (int i = tid; i < PP; i += 256) {
            unsigned int v = sv[i];
            if ((v & mask_hi) == prefix) atomicAdd(&hist[(v >> shift) & 0xFFu], 1u);
        }
        __syncthreads();
        // parallel suffix scan: hist[b] := sum_{j>=b} hist[j]
        for (int off = 1; off < 256; off <<= 1) {
            unsigned int v = hist[tid];
            unsigned int add = (tid + off < 256) ? hist[tid + off] : 0u;
            __syncthreads();
            hist[tid] = v + add;
            __syncthreads();
        }
        unsigned int suf_b  = hist[tid];
        unsigned int suf_b1 = (tid < 255) ? hist[tid + 1] : 0u;
        if (suf_b >= krem && suf_b1 < krem) {
            s_prefix = prefix | ((unsigned int)tid << shift);
            s_krem   = krem - suf_b1;
        }
        __syncthreads();
        prefix = s_prefix; krem = s_krem;
    }
    float cutoff = __uint_as_float(prefix);

    float sum_gt = 0.0f; int cnt_gt = 0;
    for (int i = tid; i < PP; i += 256) {
        float v = __uint_as_float(sv[i]);
        if (v > cutoff) { sum_gt += v; cnt_gt++; }
    }
    red_f[tid] = sum_gt; red_i[tid] = cnt_gt;
    __syncthreads();
#pragma unroll
    for (int st = 128; st > 0; st >>= 1) {
        if (tid < st) { red_f[tid] += red_f[tid + st]; red_i[tid] += red_i[tid + st]; }
        __syncthreads();
    }
    if (tid == 0)
        atomicAdd(&acc[2], red_f[0] + (float)(K - red_i[0]) * cutoff);
}

// ---------- Kernel 5: finalize ----------
__global__ void k_final(const float* __restrict__ acc,
                        const int* __restrict__ n_pos_total,
                        float* __restrict__ out)
{
    float npt = (float)(*n_pos_total);
    float loc_loss  = acc[0] / (npt * 4.0f);
    float conf_loss = (acc[1] + acc[2]) / npt;
    out[0] = conf_loss + loc_loss;
}

extern "C" void kernel_launch(void* const* d_in, const int* in_sizes, int n_in,
                              void* d_out, int out_size, void* d_ws, size_t ws_size,
                              hipStream_t stream) {
    const float* loc_pred  = (const float*)d_in[0];
    const float* cls_pred  = (const float*)d_in[1];
    const float* gt_boxes  = (const float*)d_in[2];
    const int*   gt_labels = (const int*)d_in[3];
    const float* dbox      = (const float*)d_in[4];
    float* out = (float*)d_out;

    float* acc        = (float*)d_ws;                       // 3 floats
    int*   npt        = (int*)d_ws + 3;                     // 1
    int*   n_pos      = (int*)d_ws + 4;                     // BB
    int*   bp         = (int*)d_ws + 4 + BB;                // BB*NOBJ
    int*   true_label = (int*)d_ws + 4 + BB + BB * NOBJ;    // BB*PP
    float* ce_neg     = (float*)((int*)d_ws + 4 + BB + BB * NOBJ + (size_t)BB * PP);

    hipMemsetAsync(d_ws, 0, (4 + BB) * sizeof(int), stream);

    k_bestprior<<<BB * (NOBJ / 4), 256, 0, stream>>>(gt_boxes, dbox, bp);
    k_assign<<<BB * CHUNKS, 256, 0, stream>>>(loc_pred, gt_boxes, gt_labels, dbox, bp,
                                              true_label, n_pos, acc, npt);
    k_ce<<<2048, 256, 0, stream>>>(cls_pred, true_label, ce_neg, acc);
    k_select<<<BB, 256, 0, stream>>>(ce_neg, n_pos, acc);
    k_final<<<1, 1, 0, stream>>>(acc, npt, out);
}